// Round 1
// baseline (619.871 us; speedup 1.0000x reference)
//
#include <hip/hip_runtime.h>
#include <math.h>

#define NH 32
#define HD 128
#define BS 16
#define MAXB 64
#define HID 4096
#define NBATCH 16
#define QKV_R 12288
#define SCALE 0.08838834764831845f  // 1/sqrt(128)

// y[b*R + r] = sum_j x[b*4096 + j] * W[r*4096 + j], for b in [0,16), r in [0,R)
// One block handles 4 rows; 256 threads; K=4096 hardcoded.
__global__ __launch_bounds__(256) void gemv16_k4096(
    const float* __restrict__ x, const float* __restrict__ W,
    float* __restrict__ y, int R) {
  const int r0 = blockIdx.x * 4;
  const int tid = threadIdx.x;
  const int wave = tid >> 6, lane = tid & 63;
  float acc[4][16];
#pragma unroll
  for (int r = 0; r < 4; ++r)
#pragma unroll
    for (int b = 0; b < 16; ++b) acc[r][b] = 0.f;

  for (int j = tid * 4; j < 4096; j += 1024) {
    float4 wv[4];
#pragma unroll
    for (int r = 0; r < 4; ++r)
      wv[r] = *reinterpret_cast<const float4*>(&W[(size_t)(r0 + r) * 4096 + j]);
#pragma unroll
    for (int b = 0; b < 16; ++b) {
      float4 xv = *reinterpret_cast<const float4*>(&x[b * 4096 + j]);
#pragma unroll
      for (int r = 0; r < 4; ++r) {
        acc[r][b] += wv[r].x * xv.x + wv[r].y * xv.y + wv[r].z * xv.z + wv[r].w * xv.w;
      }
    }
  }

  __shared__ float red[4][4][16];
#pragma unroll
  for (int r = 0; r < 4; ++r) {
#pragma unroll
    for (int b = 0; b < 16; ++b) {
      float v = acc[r][b];
#pragma unroll
      for (int off = 32; off; off >>= 1) v += __shfl_xor(v, off, 64);
      if (lane == 0) red[wave][r][b] = v;
    }
  }
  __syncthreads();
  if (tid < 64) {
    const int r = tid >> 4, b = tid & 15;
    const float v = red[0][r][b] + red[1][r][b] + red[2][r][b] + red[3][r][b];
    y[(size_t)b * R + r0 + r] = v;
  }
}

// One block per (b,h). Applies RoPE to this head's q,k from the qkv buffer,
// then paged-attention decode. New k/v are NOT written to the cache; they are
// substituted at s == ctx-1 (block_tables is a permutation => disjoint blocks).
__global__ __launch_bounds__(256) void attn_decode(
    const float* __restrict__ qkv, const float* __restrict__ cs_cache,
    const float* __restrict__ kcache, const float* __restrict__ vcache,
    const int* __restrict__ pos_ids, const int* __restrict__ btab,
    const int* __restrict__ ctx_len, float* __restrict__ attn_out) {
  const int b = blockIdx.x >> 5;  // / NH
  const int h = blockIdx.x & 31;  // % NH
  const int tid = threadIdx.x;
  const int wave = tid >> 6, lane = tid & 63;

  __shared__ float q_rot[HD], k_rot[HD], v_new[HD];
  __shared__ float scores[1024];
  __shared__ float redm[4], reds[4];
  __shared__ float vred[4][HD];

  const int ctx = ctx_len[b];
  const int last = ctx - 1;
  const int pos = pos_ids[b];
  const float* qp = qkv + (size_t)b * QKV_R + h * HD;
  const float* kp = qp + 4096;
  const float* vp = qp + 8192;
  const float* cs = cs_cache + (size_t)pos * HD;

  if (tid < 64) {
    const float c = cs[tid], s = cs[64 + tid];
    const float a1 = qp[tid], a2 = qp[tid + 64];
    q_rot[tid] = a1 * c - a2 * s;
    q_rot[tid + 64] = a2 * c + a1 * s;
    const float b1 = kp[tid], b2 = kp[tid + 64];
    k_rot[tid] = b1 * c - b2 * s;
    k_rot[tid + 64] = b2 * c + b1 * s;
  } else if (tid < 192) {
    const int d = tid - 64;
    v_new[d] = vp[d];
  }
  __syncthreads();

  const float2 q2 = make_float2(q_rot[2 * lane], q_rot[2 * lane + 1]);

  // Pass 1: scores
  for (int s = wave; s < ctx; s += 4) {
    float2 kv;
    if (s == last) {
      kv = make_float2(k_rot[2 * lane], k_rot[2 * lane + 1]);
    } else {
      const int blk = btab[b * MAXB + (s >> 4)];
      const float* krow = kcache + ((((size_t)blk * BS) + (s & 15)) * NH + h) * HD;
      kv = reinterpret_cast<const float2*>(krow)[lane];
    }
    float d = q2.x * kv.x + q2.y * kv.y;
#pragma unroll
    for (int off = 32; off; off >>= 1) d += __shfl_xor(d, off, 64);
    if (lane == 0) scores[s] = d * SCALE;
  }
  __syncthreads();

  // Max
  float m = -1e30f;
  for (int s = tid; s < ctx; s += 256) m = fmaxf(m, scores[s]);
#pragma unroll
  for (int off = 32; off; off >>= 1) m = fmaxf(m, __shfl_xor(m, off, 64));
  if (lane == 0) redm[wave] = m;
  __syncthreads();
  m = fmaxf(fmaxf(redm[0], redm[1]), fmaxf(redm[2], redm[3]));

  // Exp + sum
  float ssum = 0.f;
  for (int s = tid; s < ctx; s += 256) {
    const float e = expf(scores[s] - m);
    scores[s] = e;
    ssum += e;
  }
#pragma unroll
  for (int off = 32; off; off >>= 1) ssum += __shfl_xor(ssum, off, 64);
  if (lane == 0) reds[wave] = ssum;
  __syncthreads();  // also publishes exp-ed scores
  const float inv_sum = 1.f / (reds[0] + reds[1] + reds[2] + reds[3]);

  // Pass 2: P @ V
  float2 va = make_float2(0.f, 0.f);
  for (int s = wave; s < ctx; s += 4) {
    const float p = scores[s];
    float2 vv;
    if (s == last) {
      vv = make_float2(v_new[2 * lane], v_new[2 * lane + 1]);
    } else {
      const int blk = btab[b * MAXB + (s >> 4)];
      const float* vrow = vcache + ((((size_t)blk * BS) + (s & 15)) * NH + h) * HD;
      vv = reinterpret_cast<const float2*>(vrow)[lane];
    }
    va.x += p * vv.x;
    va.y += p * vv.y;
  }
  vred[wave][2 * lane] = va.x;
  vred[wave][2 * lane + 1] = va.y;
  __syncthreads();
  if (tid < HD) {
    const float o = (vred[0][tid] + vred[1][tid] + vred[2][tid] + vred[3][tid]) * inv_sum;
    attn_out[(size_t)b * HID + h * HD + tid] = o;
  }
}

extern "C" void kernel_launch(void* const* d_in, const int* in_sizes, int n_in,
                              void* d_out, int out_size, void* d_ws, size_t ws_size,
                              hipStream_t stream) {
  const float* hidden = (const float*)d_in[0];   // (16,1,4096)
  const float* qkv_w  = (const float*)d_in[1];   // (12288,4096)
  const float* out_w  = (const float*)d_in[2];   // (4096,4096)
  const float* cs     = (const float*)d_in[3];   // (2048,128)
  const float* kc     = (const float*)d_in[4];   // (1024,16,32,128)
  const float* vc     = (const float*)d_in[5];   // (1024,16,32,128)
  const int* pos      = (const int*)d_in[6];     // (16,1)
  const int* bt       = (const int*)d_in[7];     // (16,64)
  // d_in[8] = slots (unused: we substitute new k/v at s == ctx-1)
  const int* cl       = (const int*)d_in[9];     // (16,)
  float* out = (float*)d_out;                    // (16,1,4096)

  float* ws_qkv  = (float*)d_ws;                 // 16*12288 floats
  float* ws_attn = ws_qkv + NBATCH * QKV_R;      // 16*4096 floats

  gemv16_k4096<<<QKV_R / 4, 256, 0, stream>>>(hidden, qkv_w, ws_qkv, QKV_R);
  attn_decode<<<NBATCH * NH, 256, 0, stream>>>(ws_qkv, cs, kc, vc, pos, bt, cl, ws_attn);
  gemv16_k4096<<<HID / 4, 256, 0, stream>>>(ws_attn, out_w, out, HID);
}

// Round 2
// 161.285 us; speedup vs baseline: 3.8433x; 3.8433x over previous
//
#include <hip/hip_runtime.h>
#include <math.h>

#define NH 32
#define HD 128
#define BS 16
#define MAXB 64
#define HID 4096
#define NBATCH 16
#define QKV_R 12288
#define SCALE 0.08838834764831845f  // 1/sqrt(128)

// y[b*R + r] = sum_j x[b*4096+j] * W[r*4096+j].
// 8 rows per block; wave w handles batches 4w..4w+3 (acc[8][4] in regs).
__global__ __launch_bounds__(256) void gemv16_v2(
    const float* __restrict__ x, const float* __restrict__ W,
    float* __restrict__ y, int R) {
  const int r0 = blockIdx.x * 8;
  const int tid = threadIdx.x;
  const int wave = tid >> 6, lane = tid & 63;
  const int b0 = wave * 4;

  float acc[8][4];
#pragma unroll
  for (int r = 0; r < 8; ++r)
#pragma unroll
    for (int bb = 0; bb < 4; ++bb) acc[r][bb] = 0.f;

#pragma unroll 2
  for (int it = 0; it < 16; ++it) {
    const int j = it * 256 + lane * 4;
    float4 wv[8];
#pragma unroll
    for (int r = 0; r < 8; ++r)
      wv[r] = *reinterpret_cast<const float4*>(&W[(size_t)(r0 + r) * 4096 + j]);
    float4 xv[4];
#pragma unroll
    for (int bb = 0; bb < 4; ++bb)
      xv[bb] = *reinterpret_cast<const float4*>(&x[(size_t)(b0 + bb) * 4096 + j]);
#pragma unroll
    for (int r = 0; r < 8; ++r)
#pragma unroll
      for (int bb = 0; bb < 4; ++bb)
        acc[r][bb] += wv[r].x * xv[bb].x + wv[r].y * xv[bb].y +
                      wv[r].z * xv[bb].z + wv[r].w * xv[bb].w;
  }

#pragma unroll
  for (int r = 0; r < 8; ++r)
#pragma unroll
    for (int bb = 0; bb < 4; ++bb) {
      float v = acc[r][bb];
#pragma unroll
      for (int off = 32; off; off >>= 1) v += __shfl_xor(v, off, 64);
      if (lane == 0) y[(size_t)(b0 + bb) * R + r0 + r] = v;
    }
}

// One block per (b,h). 8-lane groups own tokens: lane = grp*8+sub; group loads
// a full 128-float K/V row as 4x float4 per lane (dims sub*4+i*32). New k/v
// substituted at s == ctx-1 (block_tables is a permutation => disjoint rows).
__global__ __launch_bounds__(256) void attn_decode_v2(
    const float* __restrict__ qkv, const float* __restrict__ cs_cache,
    const float* __restrict__ kcache, const float* __restrict__ vcache,
    const int* __restrict__ pos_ids, const int* __restrict__ btab,
    const int* __restrict__ ctx_len, float* __restrict__ attn_out) {
  const int b = blockIdx.x >> 5;
  const int h = blockIdx.x & 31;
  const int tid = threadIdx.x;
  const int wave = tid >> 6, lane = tid & 63;
  const int grp = lane >> 3, sub = lane & 7;
  const int gid = wave * 8 + grp;  // 0..31 token groups

  __shared__ float q_rot[HD], k_rot[HD], v_new[HD];
  __shared__ float scores[MAXB * BS];
  __shared__ int blk_base[MAXB];
  __shared__ float redm[4], reds[4];
  __shared__ float ow[4][HD];

  const int ctx = ctx_len[b];
  const int last = ctx - 1;
  const int pos = pos_ids[b];
  const float* qp = qkv + (size_t)b * QKV_R + h * HD;
  const float* kp = qp + 4096;
  const float* vp = qp + 8192;
  const float* cs = cs_cache + (size_t)pos * HD;

  if (tid < 64) {
    const float c = cs[tid], s = cs[64 + tid];
    const float a1 = qp[tid], a2 = qp[tid + 64];
    q_rot[tid] = a1 * c - a2 * s;
    q_rot[tid + 64] = a2 * c + a1 * s;
    const float b1 = kp[tid], b2 = kp[tid + 64];
    k_rot[tid] = b1 * c - b2 * s;
    k_rot[tid + 64] = b2 * c + b1 * s;
  } else if (tid < 192) {
    v_new[tid - 64] = vp[tid - 64];
  } else {
    blk_base[tid - 192] = btab[b * MAXB + (tid - 192)];
  }
  __syncthreads();

  // Per-thread q fragment (dims sub*4 + i*32)
  float4 qf[4];
#pragma unroll
  for (int i = 0; i < 4; ++i)
    qf[i] = *reinterpret_cast<const float4*>(&q_rot[sub * 4 + i * 32]);

  // Pass 1: scores (group per token, 32 tokens in flight per block)
#pragma unroll 2
  for (int t = gid; t < ctx; t += 32) {
    float4 kv[4];
    if (t == last) {
#pragma unroll
      for (int i = 0; i < 4; ++i)
        kv[i] = *reinterpret_cast<const float4*>(&k_rot[sub * 4 + i * 32]);
    } else {
      const int blk = blk_base[t >> 4];
      const float* kr = kcache + ((((size_t)blk << 4) + (t & 15)) * NH + h) * HD;
#pragma unroll
      for (int i = 0; i < 4; ++i)
        kv[i] = *reinterpret_cast<const float4*>(&kr[sub * 4 + i * 32]);
    }
    float d0 = kv[0].x * qf[0].x + kv[0].y * qf[0].y + kv[0].z * qf[0].z + kv[0].w * qf[0].w;
    float d1 = kv[1].x * qf[1].x + kv[1].y * qf[1].y + kv[1].z * qf[1].z + kv[1].w * qf[1].w;
    float d2 = kv[2].x * qf[2].x + kv[2].y * qf[2].y + kv[2].z * qf[2].z + kv[2].w * qf[2].w;
    float d3 = kv[3].x * qf[3].x + kv[3].y * qf[3].y + kv[3].z * qf[3].z + kv[3].w * qf[3].w;
    float d = (d0 + d1) + (d2 + d3);
    d += __shfl_xor(d, 1, 64);
    d += __shfl_xor(d, 2, 64);
    d += __shfl_xor(d, 4, 64);
    if (sub == 0) scores[t] = d * SCALE;
  }
  __syncthreads();

  // Max
  float m = -1e30f;
  for (int s = tid; s < ctx; s += 256) m = fmaxf(m, scores[s]);
#pragma unroll
  for (int off = 32; off; off >>= 1) m = fmaxf(m, __shfl_xor(m, off, 64));
  if (lane == 0) redm[wave] = m;
  __syncthreads();
  m = fmaxf(fmaxf(redm[0], redm[1]), fmaxf(redm[2], redm[3]));

  // Exp + sum
  float ssum = 0.f;
  for (int s = tid; s < ctx; s += 256) {
    const float e = expf(scores[s] - m);
    scores[s] = e;
    ssum += e;
  }
#pragma unroll
  for (int off = 32; off; off >>= 1) ssum += __shfl_xor(ssum, off, 64);
  if (lane == 0) reds[wave] = ssum;
  __syncthreads();
  const float inv_sum = 1.f / (reds[0] + reds[1] + reds[2] + reds[3]);

  // Pass 2: P @ V — group per token, acc 16 dims/lane, no per-token shuffles
  float4 oacc[4];
#pragma unroll
  for (int i = 0; i < 4; ++i) oacc[i] = make_float4(0.f, 0.f, 0.f, 0.f);

#pragma unroll 2
  for (int t = gid; t < ctx; t += 32) {
    const float p = scores[t];
    float4 vv[4];
    if (t == last) {
#pragma unroll
      for (int i = 0; i < 4; ++i)
        vv[i] = *reinterpret_cast<const float4*>(&v_new[sub * 4 + i * 32]);
    } else {
      const int blk = blk_base[t >> 4];
      const float* vr = vcache + ((((size_t)blk << 4) + (t & 15)) * NH + h) * HD;
#pragma unroll
      for (int i = 0; i < 4; ++i)
        vv[i] = *reinterpret_cast<const float4*>(&vr[sub * 4 + i * 32]);
    }
#pragma unroll
    for (int i = 0; i < 4; ++i) {
      oacc[i].x += p * vv[i].x;
      oacc[i].y += p * vv[i].y;
      oacc[i].z += p * vv[i].z;
      oacc[i].w += p * vv[i].w;
    }
  }

  // Cross-group butterfly within wave (xor 8,16,32 over grp bits)
#pragma unroll
  for (int i = 0; i < 4; ++i) {
#pragma unroll
    for (int off = 8; off <= 32; off <<= 1) {
      oacc[i].x += __shfl_xor(oacc[i].x, off, 64);
      oacc[i].y += __shfl_xor(oacc[i].y, off, 64);
      oacc[i].z += __shfl_xor(oacc[i].z, off, 64);
      oacc[i].w += __shfl_xor(oacc[i].w, off, 64);
    }
  }
  if (grp == 0) {
#pragma unroll
    for (int i = 0; i < 4; ++i)
      *reinterpret_cast<float4*>(&ow[wave][sub * 4 + i * 32]) = oacc[i];
  }
  __syncthreads();
  if (tid < HD) {
    const float o = (ow[0][tid] + ow[1][tid] + ow[2][tid] + ow[3][tid]) * inv_sum;
    attn_out[(size_t)b * HID + h * HD + tid] = o;
  }
}

extern "C" void kernel_launch(void* const* d_in, const int* in_sizes, int n_in,
                              void* d_out, int out_size, void* d_ws, size_t ws_size,
                              hipStream_t stream) {
  const float* hidden = (const float*)d_in[0];   // (16,1,4096)
  const float* qkv_w  = (const float*)d_in[1];   // (12288,4096)
  const float* out_w  = (const float*)d_in[2];   // (4096,4096)
  const float* cs     = (const float*)d_in[3];   // (2048,128)
  const float* kc     = (const float*)d_in[4];   // (1024,16,32,128)
  const float* vc     = (const float*)d_in[5];   // (1024,16,32,128)
  const int* pos      = (const int*)d_in[6];     // (16,1)
  const int* bt       = (const int*)d_in[7];     // (16,64)
  // d_in[8] = slots (unused: substitution at s == ctx-1)
  const int* cl       = (const int*)d_in[9];     // (16,)
  float* out = (float*)d_out;                    // (16,1,4096)

  float* ws_qkv  = (float*)d_ws;                 // 16*12288 floats
  float* ws_attn = ws_qkv + NBATCH * QKV_R;      // 16*4096 floats

  gemv16_v2<<<QKV_R / 8, 256, 0, stream>>>(hidden, qkv_w, ws_qkv, QKV_R);
  attn_decode_v2<<<NBATCH * NH, 256, 0, stream>>>(ws_qkv, cs, kc, vc, pos, bt, cl, ws_attn);
  gemv16_v2<<<HID / 8, 256, 0, stream>>>(ws_attn, out_w, out, HID);
}